// Round 5
// baseline (831.628 us; speedup 1.0000x reference)
//
#include <hip/hip_runtime.h>

#define HID   15
#define TMAIN 1024
#define FUT   64
#define OUTW  (TMAIN + FUT)   // 1088

__device__ __forceinline__ float rcp_(float x)  { return __builtin_amdgcn_rcpf(x); }
__device__ __forceinline__ float exp2_(float x) { return __builtin_amdgcn_exp2f(x); }
__device__ __forceinline__ float tanh_(float x) {
    return __builtin_fmaf(2.0f, rcp_(1.0f + exp2_(x * -2.885390081777927f)), -1.0f);
}

template<int I> struct ic { static constexpr int v = I; };
template<int J, int N, class F>
__device__ __forceinline__ void unroll_for(F&& f) {
    if constexpr (J < N) { f(ic<J>{}); unroll_for<J + 1, N>(f); }
}

// DPP ctrl: 0x150+j = row_newbcast:j (CDNA), 0x110+n = row_shr:n
template<int CTRL>
__device__ __forceinline__ float dppf(float x) {
    return __int_as_float(__builtin_amdgcn_update_dpp(
        0, __float_as_int(x), CTRL, 0xF, 0xF, true));
}
__device__ __forceinline__ float row_sum_bcast(float p) {
    p += dppf<0x111>(p);
    p += dppf<0x112>(p);
    p += dppf<0x114>(p);
    p += dppf<0x118>(p);
    return dppf<0x15F>(p); // row_newbcast:15
}

// R5 mapping: 1 wave = 2 batches; lane = g*32 + r*16 + k.
//   g = batch (each 16-lane DPP row belongs to one batch), r = gate-pair half
//   (r=0: gates i,f; r=1: gates g,o), k = hidden unit (15 = pad, zero weights).
// Why n=2 (vs R4's n=4): per-lane weights 180 -> 90, total reg demand ~125 fits
// the observed 132-arch-VGPR allocation -> no v_accvgpr copy traffic (R4's ~2x
// VALU inflation); and 2048 waves = 2/SIMD hides trans-pipe (quarter-rate
// exp2/rcp) + DPP bubbles + xs-read waits that were exposed at 1 wave/SIMD.
// r-exchange: i*g = va*va2 is symmetric -> product needs NO select; only f/o
// need 1 cndmask each. Both halves recompute c/h bit-identically.
// All h broadcasts are DPP row_newbcast (no LDS in recurrence); act scales
// (-log2e / -2log2e) folded into weights; out dot = DPP row reduction.
__global__ __launch_bounds__(256)
__attribute__((amdgpu_waves_per_eu(2, 2)))
void lstm_seq_kernel(const float* __restrict__ input,
                     const float* __restrict__ W_ih1, const float* __restrict__ W_hh1,
                     const float* __restrict__ b_ih1, const float* __restrict__ b_hh1,
                     const float* __restrict__ W_ih2, const float* __restrict__ W_hh2,
                     const float* __restrict__ b_ih2, const float* __restrict__ b_hh2,
                     const float* __restrict__ W_lin, const float* __restrict__ b_lin,
                     float* __restrict__ out)
{
    __shared__ float xs[4][2][64];   // [wave][batch][t] staged input tile
    __shared__ float os[4][2][64];   // output tile

    const int tid  = threadIdx.x;
    const int wq   = tid >> 6;
    const int lane = tid & 63;
    const int g    = lane >> 5;         // batch in wave
    const int r    = (lane >> 4) & 1;   // gate-pair half
    const int k    = lane & 15;         // hidden unit (15 = pad)
    const int b0   = (blockIdx.x * 4 + wq) * 2;

    const bool pad = (k >= HID);
    const float m  = pad ? 0.0f : 1.0f;
    const int  kk  = pad ? 0 : k;

    const float L2E = 1.442695040888963f;
    const float sA  = m * (r ? -2.0f * L2E : -L2E);  // row A: i(sigm) / g(tanh)
    const float sB  = m * -L2E;                      // row B: f / o (sigm)

    const int rowA = (r ? 2 : 0) * HID + kk;   // gate i or g
    const int rowB = (r ? 3 : 1) * HID + kk;   // gate f or o

    float w1a[HID], w1b[HID], w2ia[HID], w2ib[HID], w2ha[HID], w2hb[HID];
    #pragma unroll
    for (int j = 0; j < HID; ++j) {
        w1a [j] = sA * W_hh1[rowA * HID + j];
        w1b [j] = sB * W_hh1[rowB * HID + j];
        w2ia[j] = sA * W_ih2[rowA * HID + j];
        w2ib[j] = sB * W_ih2[rowB * HID + j];
        w2ha[j] = sA * W_hh2[rowA * HID + j];
        w2hb[j] = sB * W_hh2[rowB * HID + j];
    }
    const float wihA = sA * W_ih1[rowA];
    const float wihB = sB * W_ih1[rowB];
    const float bA1  = sA * (b_ih1[rowA] + b_hh1[rowA]);
    const float bB1  = sB * (b_ih1[rowB] + b_hh1[rowB]);
    const float bA2  = sA * (b_ih2[rowA] + b_hh2[rowA]);
    const float bB2  = sB * (b_ih2[rowB] + b_hh2[rowB]);
    const float wl   = m * W_lin[kk];
    const float blin = b_lin[0];

    // act A: sigm on r=0, tanh on r=1: act = fma(Aa, rcp(1+exp2(a)), Ca)
    const float Aa = r ? 2.0f : 1.0f;
    const float Ca = r ? -1.0f : 0.0f;
    const bool  hi = (r != 0);

    float h1p = 0.0f, h2p = 0.0f;   // own unit's h (this batch), both halves equal
    float c1 = 0.0f, c2 = 0.0f, outv = 0.0f;

    auto step = [&](float x, int c) {
        // ---- layer-1 pre-acts ----
        float aA = __builtin_fmaf(wihA, x, bA1);
        float aB = __builtin_fmaf(wihB, x, bB1);
        unroll_for<0, HID>([&](auto jc) {
            constexpr int j = decltype(jc)::v;
            const float hb = dppf<0x150 + j>(h1p);
            aA = __builtin_fmaf(w1a[j], hb, aA);
            aB = __builtin_fmaf(w1b[j], hb, aB);
        });

        // ---- layer-2 hh part (only needs prev h2; overlaps L1 act latency) ----
        float dA = bA2, dB = bB2;
        unroll_for<0, HID>([&](auto jc) {
            constexpr int j = decltype(jc)::v;
            const float hb = dppf<0x150 + j>(h2p);
            dA = __builtin_fmaf(w2ha[j], hb, dA);
            dB = __builtin_fmaf(w2hb[j], hb, dB);
        });

        // ---- layer-1 activations + half exchange ----
        const float va  = __builtin_fmaf(Aa, rcp_(1.0f + exp2_(aA)), Ca);
        const float vb  = rcp_(1.0f + exp2_(aB));
        const float va2 = __shfl_xor(va, 16);
        const float vb2 = __shfl_xor(vb, 16);
        const float f1  = hi ? vb2 : vb;    // gate f (computed by r=0 half)
        const float o1  = hi ? vb : vb2;    // gate o (computed by r=1 half)
        c1 = __builtin_fmaf(f1, c1, va * va2);   // i*g symmetric: no select
        const float h1n = o1 * tanh_(c1);

        // ---- layer-2 ih part ----
        unroll_for<0, HID>([&](auto jc) {
            constexpr int j = decltype(jc)::v;
            const float hb = dppf<0x150 + j>(h1n);
            dA = __builtin_fmaf(w2ia[j], hb, dA);
            dB = __builtin_fmaf(w2ib[j], hb, dB);
        });

        // ---- layer-2 activations + exchange ----
        const float ua  = __builtin_fmaf(Aa, rcp_(1.0f + exp2_(dA)), Ca);
        const float ub  = rcp_(1.0f + exp2_(dB));
        const float ua2 = __shfl_xor(ua, 16);
        const float ub2 = __shfl_xor(ub, 16);
        const float f2  = hi ? ub2 : ub;
        const float o2  = hi ? ub : ub2;
        c2 = __builtin_fmaf(f2, c2, ua * ua2);
        const float h2n = o2 * tanh_(c2);

        // ---- out = <W_lin, h2> + b via DPP row reduction ----
        const float ov = row_sum_bcast(wl * h2n) + blin;
        os[wq][g][c] = ov;              // 32 lanes same addr/value: OK

        h1p = h1n; h2p = h2n; outv = ov;
    };

    // ---- main T steps, tiles of 64 ----
    #pragma unroll 1
    for (int tile = 0; tile < TMAIN / 64; ++tile) {
        const int t0 = tile * 64;
        #pragma unroll
        for (int j = 0; j < 2; ++j)
            xs[wq][j][lane] = input[(size_t)(b0 + j) * TMAIN + t0 + lane];
        #pragma unroll 2
        for (int c = 0; c < 64; ++c)
            step(xs[wq][g][c], c);
        #pragma unroll
        for (int j = 0; j < 2; ++j)
            out[(size_t)(b0 + j) * OUTW + t0 + lane] = os[wq][j][lane];
    }

    // ---- autoregressive future steps: x = previous out (in-lane) ----
    #pragma unroll 1
    for (int c = 0; c < FUT; ++c)
        step(outv, c);
    #pragma unroll
    for (int j = 0; j < 2; ++j)
        out[(size_t)(b0 + j) * OUTW + TMAIN + lane] = os[wq][j][lane];
}

extern "C" void kernel_launch(void* const* d_in, const int* in_sizes, int n_in,
                              void* d_out, int out_size, void* d_ws, size_t ws_size,
                              hipStream_t stream)
{
    const float* input = (const float*)d_in[0];
    const float* W_ih1 = (const float*)d_in[1];
    const float* W_hh1 = (const float*)d_in[2];
    const float* b_ih1 = (const float*)d_in[3];
    const float* b_hh1 = (const float*)d_in[4];
    const float* W_ih2 = (const float*)d_in[5];
    const float* W_hh2 = (const float*)d_in[6];
    const float* b_ih2 = (const float*)d_in[7];
    const float* b_hh2 = (const float*)d_in[8];
    const float* W_lin = (const float*)d_in[9];
    const float* b_lin = (const float*)d_in[10];
    // d_in[11] = future (=64), compiled in as FUT

    // 4096 batches / (2 per wave * 4 waves per block) = 512 blocks
    lstm_seq_kernel<<<512, 256, 0, stream>>>(
        input, W_ih1, W_hh1, b_ih1, b_hh1,
        W_ih2, W_hh2, b_ih2, b_hh2, W_lin, b_lin,
        (float*)d_out);
}

// Round 6
// 596.321 us; speedup vs baseline: 1.3946x; 1.3946x over previous
//
#include <hip/hip_runtime.h>

#define HID   15
#define TMAIN 1024
#define FUT   64
#define OUTW  (TMAIN + FUT)   // 1088

typedef float v2f __attribute__((ext_vector_type(2)));

__device__ __forceinline__ float rcp_(float x)  { return __builtin_amdgcn_rcpf(x); }
__device__ __forceinline__ float exp2_(float x) { return __builtin_amdgcn_exp2f(x); }
__device__ __forceinline__ float tanh_(float x) {
    return __builtin_fmaf(2.0f, rcp_(1.0f + exp2_(x * -2.885390081777927f)), -1.0f);
}

template<int I> struct ic { static constexpr int v = I; };
template<int J, int N, class F>
__device__ __forceinline__ void unroll_for(F&& f) {
    if constexpr (J < N) { f(ic<J>{}); unroll_for<J + 1, N>(f); }
}

// DPP ctrl: 0x150+j = row_newbcast:j (CDNA), 0x110+n = row_shr:n
template<int CTRL>
__device__ __forceinline__ float dppf(float x) {
    return __int_as_float(__builtin_amdgcn_update_dpp(
        0, __float_as_int(x), CTRL, 0xF, 0xF, true));
}
__device__ __forceinline__ float row_sum_bcast(float p) {
    p += dppf<0x111>(p);
    p += dppf<0x112>(p);
    p += dppf<0x114>(p);
    p += dppf<0x118>(p);
    return dppf<0x15F>(p); // row_newbcast:15
}

// one packed fp32 FMA: a.lo += w.lo*h.lo ; a.hi += w.hi*h.hi  (exact fp32)
__device__ __forceinline__ void pkfma(v2f& a, v2f w, v2f h) {
    asm("v_pk_fma_f32 %0, %1, %2, %0" : "+v"(a) : "v"(w), "v"(h));
}

// build broadcast pair {h[2J], h[2J+1]} replicated across each 16-lane row.
// J=7 pairs {h[14], h[15]}; lane15's h is exactly 0 (zero weights keep its
// c/h at 0 through the recurrence), and its weight is 0 too.
template<int J>
__device__ __forceinline__ v2f bpair(float h) {
    v2f p;
    p.x = dppf<0x150 + 2*J>(h);
    p.y = dppf<0x150 + 2*J + 1>(h);
    return p;
}

// R6 = R4 (n=4 mapping: 1 wave = 4 batches; lane = g*16+k; g = batch = DPP row,
// k = unit, 15 = pad) with the matvec FMAs packed into v_pk_fma_f32:
// 184 scalar FMA -> 96 pk + 12 horizontal adds. h broadcasts as pairs (2 DPP
// per pair); hb1 pairs built once per step after h1n and reused by BOTH L2-ih
// (this step) and L1-hh (next step): 45 DPP -> 32. os store masked to k==0
// (removes the same-address write serialization, 1.18e6 conflicts).
// R5 lesson: n=4 single-wave is instruction-minimal — one DPP/weight serves 4
// batches; stay here and shrink the instruction stream instead.
__global__ __launch_bounds__(256)
__attribute__((amdgpu_waves_per_eu(1, 1)))
void lstm_seq_kernel(const float* __restrict__ input,
                     const float* __restrict__ W_ih1, const float* __restrict__ W_hh1,
                     const float* __restrict__ b_ih1, const float* __restrict__ b_hh1,
                     const float* __restrict__ W_ih2, const float* __restrict__ W_hh2,
                     const float* __restrict__ b_ih2, const float* __restrict__ b_hh2,
                     const float* __restrict__ W_lin, const float* __restrict__ b_lin,
                     float* __restrict__ out)
{
    __shared__ float xs[4][4][64];   // [wave][batch][t] staged input tile
    __shared__ float os[4][4][64];   // output tile

    const int tid  = threadIdx.x;
    const int wq   = tid >> 6;
    const int lane = tid & 63;
    const int g    = lane >> 4;       // batch subgroup == DPP row
    const int k    = lane & 15;       // hidden unit (15 = pad)
    const int b0   = (blockIdx.x * 4 + wq) * 4;

    const bool pad = (k >= HID);
    const float m  = pad ? 0.0f : 1.0f;
    const int  kk  = pad ? 0 : k;

    // act-input scale per gate (i,f,g,o): sigm rows -log2e, tanh row -2log2e
    const float L2E = 1.442695040888963f;
    const float sA[4] = {-L2E, -L2E, -2.0f * L2E, -L2E};

    // packed weight pairs: [gate][pair j] = {w[2j], w[2j+1]}, elem 15 = 0
    v2f w1[4][8], w2i[4][8], w2h[4][8];
    float wih1[4], bb1[4], bb2[4];
    #pragma unroll
    for (int gi = 0; gi < 4; ++gi) {
        const int row = gi * HID + kk;
        const float s = m * sA[gi];
        wih1[gi] = s * W_ih1[row];
        bb1[gi]  = s * (b_ih1[row] + b_hh1[row]);
        bb2[gi]  = s * (b_ih2[row] + b_hh2[row]);
        #pragma unroll
        for (int j = 0; j < 8; ++j) {
            const int c0 = 2 * j, c1i = 2 * j + 1;
            w1 [gi][j].x = s * W_hh1[row * HID + c0];
            w1 [gi][j].y = (c1i < HID) ? s * W_hh1[row * HID + c1i] : 0.0f;
            w2i[gi][j].x = s * W_ih2[row * HID + c0];
            w2i[gi][j].y = (c1i < HID) ? s * W_ih2[row * HID + c1i] : 0.0f;
            w2h[gi][j].x = s * W_hh2[row * HID + c0];
            w2h[gi][j].y = (c1i < HID) ? s * W_hh2[row * HID + c1i] : 0.0f;
        }
    }
    const float wl   = m * W_lin[kk];
    const float blin = b_lin[0];

    float h2p = 0.0f;                 // own unit's h2 (pairs built at use site)
    v2f hb1[8];                       // h1 broadcast pairs, live across steps
    #pragma unroll
    for (int j = 0; j < 8; ++j) hb1[j] = (v2f){0.0f, 0.0f};
    float c1 = 0.0f, c2 = 0.0f, outv = 0.0f;

    auto step = [&](float x, int c) {
        // ---- layer-1 pre-acts: uses hb1 built at the END of previous step ----
        v2f A0, A1, A2, A3;
        A0.x = __builtin_fmaf(wih1[0], x, bb1[0]); A0.y = 0.0f;
        A1.x = __builtin_fmaf(wih1[1], x, bb1[1]); A1.y = 0.0f;
        A2.x = __builtin_fmaf(wih1[2], x, bb1[2]); A2.y = 0.0f;
        A3.x = __builtin_fmaf(wih1[3], x, bb1[3]); A3.y = 0.0f;
        unroll_for<0, 8>([&](auto jc) {
            constexpr int j = decltype(jc)::v;
            pkfma(A0, w1[0][j], hb1[j]);
            pkfma(A1, w1[1][j], hb1[j]);
            pkfma(A2, w1[2][j], hb1[j]);
            pkfma(A3, w1[3][j], hb1[j]);
        });
        const float a0 = A0.x + A0.y, a1 = A1.x + A1.y;
        const float a2 = A2.x + A2.y, a3 = A3.x + A3.y;

        // ---- layer-2 hh part (prev h2; overlaps L1 act latency below) ----
        v2f D0, D1, D2, D3;
        D0.x = bb2[0]; D0.y = 0.0f;
        D1.x = bb2[1]; D1.y = 0.0f;
        D2.x = bb2[2]; D2.y = 0.0f;
        D3.x = bb2[3]; D3.y = 0.0f;
        unroll_for<0, 8>([&](auto jc) {
            constexpr int j = decltype(jc)::v;
            const v2f hb = bpair<j>(h2p);
            pkfma(D0, w2h[0][j], hb);
            pkfma(D1, w2h[1][j], hb);
            pkfma(D2, w2h[2][j], hb);
            pkfma(D3, w2h[3][j], hb);
        });

        // ---- layer-1 activations, c1, h1 ----
        const float ig = rcp_(1.0f + exp2_(a0));
        const float fg = rcp_(1.0f + exp2_(a1));
        const float gg = __builtin_fmaf(2.0f, rcp_(1.0f + exp2_(a2)), -1.0f);
        const float og = rcp_(1.0f + exp2_(a3));
        c1 = __builtin_fmaf(fg, c1, ig * gg);
        const float h1n = og * tanh_(c1);

        // ---- build hb1 pairs ONCE (used by L2-ih now and L1-hh next step) ----
        unroll_for<0, 8>([&](auto jc) {
            constexpr int j = decltype(jc)::v;
            hb1[j] = bpair<j>(h1n);
        });
        unroll_for<0, 8>([&](auto jc) {
            constexpr int j = decltype(jc)::v;
            pkfma(D0, w2i[0][j], hb1[j]);
            pkfma(D1, w2i[1][j], hb1[j]);
            pkfma(D2, w2i[2][j], hb1[j]);
            pkfma(D3, w2i[3][j], hb1[j]);
        });
        const float d0 = D0.x + D0.y, d1 = D1.x + D1.y;
        const float d2 = D2.x + D2.y, d3 = D3.x + D3.y;

        // ---- layer-2 activations, c2, h2 ----
        const float i2 = rcp_(1.0f + exp2_(d0));
        const float f2 = rcp_(1.0f + exp2_(d1));
        const float g2 = __builtin_fmaf(2.0f, rcp_(1.0f + exp2_(d2)), -1.0f);
        const float o2 = rcp_(1.0f + exp2_(d3));
        c2 = __builtin_fmaf(f2, c2, i2 * g2);
        const float h2n = o2 * tanh_(c2);

        // ---- out = <W_lin, h2> + b via DPP row reduction ----
        const float ov = row_sum_bcast(wl * h2n) + blin;
        if (k == 0) os[wq][g][c] = ov;   // one lane per row: no write conflicts

        h2p = h2n; outv = ov;
    };

    // ---- main T steps, tiles of 64 ----
    #pragma unroll 1
    for (int tile = 0; tile < TMAIN / 64; ++tile) {
        const int t0 = tile * 64;
        #pragma unroll
        for (int j = 0; j < 4; ++j)
            xs[wq][j][lane] = input[(size_t)(b0 + j) * TMAIN + t0 + lane];
        __builtin_amdgcn_s_waitcnt(0);   // lgkm drain before first xs read
        #pragma unroll 2
        for (int c = 0; c < 64; ++c)
            step(xs[wq][g][c], c);
        #pragma unroll
        for (int j = 0; j < 4; ++j)
            out[(size_t)(b0 + j) * OUTW + t0 + lane] = os[wq][j][lane];
    }

    // ---- autoregressive future steps: x = previous out (in-lane) ----
    #pragma unroll 1
    for (int c = 0; c < FUT; ++c)
        step(outv, c);
    #pragma unroll
    for (int j = 0; j < 4; ++j)
        out[(size_t)(b0 + j) * OUTW + TMAIN + lane] = os[wq][j][lane];
}

extern "C" void kernel_launch(void* const* d_in, const int* in_sizes, int n_in,
                              void* d_out, int out_size, void* d_ws, size_t ws_size,
                              hipStream_t stream)
{
    const float* input = (const float*)d_in[0];
    const float* W_ih1 = (const float*)d_in[1];
    const float* W_hh1 = (const float*)d_in[2];
    const float* b_ih1 = (const float*)d_in[3];
    const float* b_hh1 = (const float*)d_in[4];
    const float* W_ih2 = (const float*)d_in[5];
    const float* W_hh2 = (const float*)d_in[6];
    const float* b_ih2 = (const float*)d_in[7];
    const float* b_hh2 = (const float*)d_in[8];
    const float* W_lin = (const float*)d_in[9];
    const float* b_lin = (const float*)d_in[10];
    // d_in[11] = future (=64), compiled in as FUT

    // 4096 batches / (4 per wave * 4 waves per block) = 256 blocks
    lstm_seq_kernel<<<256, 256, 0, stream>>>(
        input, W_ih1, W_hh1, b_ih1, b_hh1,
        W_ih2, W_hh2, b_ih2, b_hh2, W_lin, b_lin,
        (float*)d_out);
}

// Round 7
// 545.813 us; speedup vs baseline: 1.5236x; 1.0925x over previous
//
#include <hip/hip_runtime.h>

#define HID   15
#define TMAIN 1024
#define FUT   64
#define OUTW  (TMAIN + FUT)   // 1088

typedef float v2f __attribute__((ext_vector_type(2)));

__device__ __forceinline__ float rcp_(float x)  { return __builtin_amdgcn_rcpf(x); }
__device__ __forceinline__ float exp2_(float x) { return __builtin_amdgcn_exp2f(x); }
__device__ __forceinline__ float tanh_(float x) {
    return __builtin_fmaf(2.0f, rcp_(1.0f + exp2_(x * -2.885390081777927f)), -1.0f);
}

template<int I> struct ic { static constexpr int v = I; };
template<int J, int N, class F>
__device__ __forceinline__ void unroll_for(F&& f) {
    if constexpr (J < N) { f(ic<J>{}); unroll_for<J + 1, N>(f); }
}

// DPP ctrl: 0x150+j = row_newbcast:j (CDNA), 0x110+n = row_shr:n
template<int CTRL>
__device__ __forceinline__ float dppf(float x) {
    return __int_as_float(__builtin_amdgcn_update_dpp(
        0, __float_as_int(x), CTRL, 0xF, 0xF, true));
}
__device__ __forceinline__ float row_sum_bcast(float p) {
    p += dppf<0x111>(p);
    p += dppf<0x112>(p);
    p += dppf<0x114>(p);
    p += dppf<0x118>(p);
    return dppf<0x15F>(p); // lane15 of each row has the sum -> bcast
}

// broadcast pair {h[2J], h[2J+1]} across each 16-lane row (lane15's h == 0)
template<int J>
__device__ __forceinline__ v2f bpair(float h) {
    v2f p;
    p.x = dppf<0x150 + 2*J>(h);
    p.y = dppf<0x150 + 2*J + 1>(h);
    return p;
}

// R7 = R6 (n=4 mapping, packed-pair matvecs, DPP h broadcasts) with ALL LDS
// traffic removed from the recurrence:
//  - x: lane (g,k) holds x[b0+g][tc+k] for a 16-step chunk (coalesced global
//    load, prefetched one chunk = ~10k cyc ahead); per-substep broadcast is one
//    compile-time row_newbcast:s DPP. Kills the per-step ds_read + its exposed
//    lgkm wait + the 4-way bank conflict (R6: 4.3M conflict cycles).
//  - out: ov selected into oreg when k==s (cndmask), stored coalesced once per
//    16 steps. No os tile.
//  - pk FMAs as native v2f arithmetic (compiler emits v_pk_fma_f32 itself;
//    R6's inline asm pinned operands to arch VGPRs and blocked scheduling).
__global__ __launch_bounds__(256)
__attribute__((amdgpu_waves_per_eu(1, 1)))
void lstm_seq_kernel(const float* __restrict__ input,
                     const float* __restrict__ W_ih1, const float* __restrict__ W_hh1,
                     const float* __restrict__ b_ih1, const float* __restrict__ b_hh1,
                     const float* __restrict__ W_ih2, const float* __restrict__ W_hh2,
                     const float* __restrict__ b_ih2, const float* __restrict__ b_hh2,
                     const float* __restrict__ W_lin, const float* __restrict__ b_lin,
                     float* __restrict__ out)
{
    const int tid  = threadIdx.x;
    const int wq   = tid >> 6;
    const int lane = tid & 63;
    const int g    = lane >> 4;       // batch subgroup == DPP row
    const int k    = lane & 15;       // hidden unit / time-slot (15 = pad unit)
    const int b0   = (blockIdx.x * 4 + wq) * 4;

    const bool pad = (k >= HID);
    const float m  = pad ? 0.0f : 1.0f;
    const int  kk  = pad ? 0 : k;

    // act-input scale per gate (i,f,g,o): sigm rows -log2e, tanh row -2log2e
    const float L2E = 1.442695040888963f;
    const float sA[4] = {-L2E, -L2E, -2.0f * L2E, -L2E};

    // packed weight pairs: [gate][pair j] = {w[2j], w[2j+1]}, elem 15 = 0
    v2f w1[4][8], w2i[4][8], w2h[4][8];
    float wih1[4], bb1[4], bb2[4];
    #pragma unroll
    for (int gi = 0; gi < 4; ++gi) {
        const int row = gi * HID + kk;
        const float s = m * sA[gi];
        wih1[gi] = s * W_ih1[row];
        bb1[gi]  = s * (b_ih1[row] + b_hh1[row]);
        bb2[gi]  = s * (b_ih2[row] + b_hh2[row]);
        #pragma unroll
        for (int j = 0; j < 8; ++j) {
            const int c0 = 2 * j, c1i = 2 * j + 1;
            w1 [gi][j].x = s * W_hh1[row * HID + c0];
            w1 [gi][j].y = (c1i < HID) ? s * W_hh1[row * HID + c1i] : 0.0f;
            w2i[gi][j].x = s * W_ih2[row * HID + c0];
            w2i[gi][j].y = (c1i < HID) ? s * W_ih2[row * HID + c1i] : 0.0f;
            w2h[gi][j].x = s * W_hh2[row * HID + c0];
            w2h[gi][j].y = (c1i < HID) ? s * W_hh2[row * HID + c1i] : 0.0f;
        }
    }
    const float wl   = m * W_lin[kk];
    const float blin = b_lin[0];

    float h2p = 0.0f;                 // own unit's h2 (pairs built at use site)
    v2f hb1[8];                       // h1 broadcast pairs, live across steps
    #pragma unroll
    for (int j = 0; j < 8; ++j) hb1[j] = (v2f){0.0f, 0.0f};
    float c1 = 0.0f, c2 = 0.0f, outv = 0.0f;

    // one LSTM step; sub = position in 16-chunk (runtime int is fine here —
    // only the x/h DPP broadcasts need compile-time ctrl, handled by callers)
    auto step = [&](float x, int sub, float& oreg) {
        // ---- layer-1 pre-acts: uses hb1 built at the END of previous step ----
        v2f A0 = {__builtin_fmaf(wih1[0], x, bb1[0]), 0.0f};
        v2f A1 = {__builtin_fmaf(wih1[1], x, bb1[1]), 0.0f};
        v2f A2 = {__builtin_fmaf(wih1[2], x, bb1[2]), 0.0f};
        v2f A3 = {__builtin_fmaf(wih1[3], x, bb1[3]), 0.0f};
        unroll_for<0, 8>([&](auto jc) {
            constexpr int j = decltype(jc)::v;
            A0 += w1[0][j] * hb1[j];
            A1 += w1[1][j] * hb1[j];
            A2 += w1[2][j] * hb1[j];
            A3 += w1[3][j] * hb1[j];
        });
        const float a0 = A0.x + A0.y, a1 = A1.x + A1.y;
        const float a2 = A2.x + A2.y, a3 = A3.x + A3.y;

        // ---- layer-2 hh part (prev h2; overlaps L1 act latency below) ----
        v2f D0 = {bb2[0], 0.0f}, D1 = {bb2[1], 0.0f};
        v2f D2 = {bb2[2], 0.0f}, D3 = {bb2[3], 0.0f};
        unroll_for<0, 8>([&](auto jc) {
            constexpr int j = decltype(jc)::v;
            const v2f hb = bpair<j>(h2p);
            D0 += w2h[0][j] * hb;
            D1 += w2h[1][j] * hb;
            D2 += w2h[2][j] * hb;
            D3 += w2h[3][j] * hb;
        });

        // ---- layer-1 activations, c1, h1 ----
        const float ig = rcp_(1.0f + exp2_(a0));
        const float fg = rcp_(1.0f + exp2_(a1));
        const float gg = __builtin_fmaf(2.0f, rcp_(1.0f + exp2_(a2)), -1.0f);
        const float og = rcp_(1.0f + exp2_(a3));
        c1 = __builtin_fmaf(fg, c1, ig * gg);
        const float h1n = og * tanh_(c1);

        // ---- build hb1 pairs ONCE (used by L2-ih now and L1-hh next step) ----
        unroll_for<0, 8>([&](auto jc) {
            constexpr int j = decltype(jc)::v;
            hb1[j] = bpair<j>(h1n);
        });
        unroll_for<0, 8>([&](auto jc) {
            constexpr int j = decltype(jc)::v;
            D0 += w2i[0][j] * hb1[j];
            D1 += w2i[1][j] * hb1[j];
            D2 += w2i[2][j] * hb1[j];
            D3 += w2i[3][j] * hb1[j];
        });
        const float d0 = D0.x + D0.y, d1 = D1.x + D1.y;
        const float d2 = D2.x + D2.y, d3 = D3.x + D3.y;

        // ---- layer-2 activations, c2, h2 ----
        const float i2 = rcp_(1.0f + exp2_(d0));
        const float f2 = rcp_(1.0f + exp2_(d1));
        const float g2 = __builtin_fmaf(2.0f, rcp_(1.0f + exp2_(d2)), -1.0f);
        const float o2 = rcp_(1.0f + exp2_(d3));
        c2 = __builtin_fmaf(f2, c2, i2 * g2);
        const float h2n = o2 * tanh_(c2);

        // ---- out = <W_lin, h2> + b via DPP row reduction; keep own slot ----
        const float ov = row_sum_bcast(wl * h2n) + blin;
        oreg = (k == sub) ? ov : oreg;

        h2p = h2n; outv = ov;
    };

    const size_t inb  = (size_t)(b0 + g) * TMAIN + k;
    const size_t outb = (size_t)(b0 + g) * OUTW  + k;

    // ---- main: 64 chunks of 16 steps; x prefetched one chunk ahead ----
    float xnext = input[inb];
    #pragma unroll 1
    for (int ch = 0; ch < TMAIN / 16; ++ch) {
        const float xcur = xnext;
        const int tn = (ch < TMAIN / 16 - 1) ? (ch + 1) * 16 : ch * 16; // clamped
        xnext = input[inb + tn];
        float oreg = 0.0f;
        unroll_for<0, 16>([&](auto sc) {
            constexpr int s = decltype(sc)::v;
            step(dppf<0x150 + s>(xcur), s, oreg);   // x[tc+s] bcast to the row
        });
        out[outb + ch * 16] = oreg;                 // coalesced, 16 t per lane
    }

    // ---- future: x = previous out (row-uniform in outv already) ----
    #pragma unroll 1
    for (int ch = 0; ch < FUT / 16; ++ch) {
        float oreg = 0.0f;
        unroll_for<0, 16>([&](auto sc) {
            constexpr int s = decltype(sc)::v;
            step(outv, s, oreg);
        });
        out[outb + TMAIN + ch * 16] = oreg;
    }
}

extern "C" void kernel_launch(void* const* d_in, const int* in_sizes, int n_in,
                              void* d_out, int out_size, void* d_ws, size_t ws_size,
                              hipStream_t stream)
{
    const float* input = (const float*)d_in[0];
    const float* W_ih1 = (const float*)d_in[1];
    const float* W_hh1 = (const float*)d_in[2];
    const float* b_ih1 = (const float*)d_in[3];
    const float* b_hh1 = (const float*)d_in[4];
    const float* W_ih2 = (const float*)d_in[5];
    const float* W_hh2 = (const float*)d_in[6];
    const float* b_ih2 = (const float*)d_in[7];
    const float* b_hh2 = (const float*)d_in[8];
    const float* W_lin = (const float*)d_in[9];
    const float* b_lin = (const float*)d_in[10];
    // d_in[11] = future (=64), compiled in as FUT

    // 4096 batches / (4 per wave * 4 waves per block) = 256 blocks
    lstm_seq_kernel<<<256, 256, 0, stream>>>(
        input, W_ih1, W_hh1, b_ih1, b_hh1,
        W_ih2, W_hh2, b_ih2, b_hh2, W_lin, b_lin,
        (float*)d_out);
}

// Round 8
// 477.281 us; speedup vs baseline: 1.7424x; 1.1436x over previous
//
#include <hip/hip_runtime.h>

#define HID   15
#define TMAIN 1024
#define FUT   64
#define OUTW  (TMAIN + FUT)   // 1088

typedef _Float16 v2h __attribute__((ext_vector_type(2)));

__device__ __forceinline__ float rcp_(float x)  { return __builtin_amdgcn_rcpf(x); }
__device__ __forceinline__ float exp2_(float x) { return __builtin_amdgcn_exp2f(x); }
__device__ __forceinline__ float tanh_(float x) {
    return __builtin_fmaf(2.0f, rcp_(1.0f + exp2_(x * -2.885390081777927f)), -1.0f);
}

template<int I> struct ic { static constexpr int v = I; };
template<int J, int N, class F>
__device__ __forceinline__ void unroll_for(F&& f) {
    if constexpr (J < N) { f(ic<J>{}); unroll_for<J + 1, N>(f); }
}

// DPP ctrl: 0x150+j = row_newbcast:j (CDNA), 0x110+n = row_shr:n, 0x100+n = row_shl:n
template<int CTRL>
__device__ __forceinline__ int dppi(int x) {
    return __builtin_amdgcn_update_dpp(0, x, CTRL, 0xF, 0xF, true);
}
template<int CTRL>
__device__ __forceinline__ float dppf(float x) {
    return __int_as_float(dppi<CTRL>(__float_as_int(x)));
}
__device__ __forceinline__ float row_sum_bcast(float p) {
    p += dppf<0x111>(p);
    p += dppf<0x112>(p);
    p += dppf<0x114>(p);
    p += dppf<0x118>(p);
    return dppf<0x15F>(p); // lane15 of each row has the sum -> bcast
}

__device__ __forceinline__ float fdot2(v2h a, v2h b, float c) {
    return __builtin_amdgcn_fdot2(a, b, c, false);
}

// R8 = R7 (n=4 mapping, all-register, DPP broadcasts) with the matvec moved to
// v_dot2_f32_f16: fp16 multiplies (weights+h quantized RNE), fp32 accumulate,
// FULL-rate (2cyc) vs half-rate v_pk_fma_f32 (R7 lesson: fp32 pk is 4 cyc —
// 157.3 TF spec is the scalar rate). 96 dot2 = 192 cyc vs 384, horizontal adds
// gone (dot2 reduces), weight regs halve (96->48). h broadcast in packed-fp16
// form: cvt + row_shl:1 + pack (3 ops) builds lane k = {h16[k], h16[k+1]}, then
// ONE row_newbcast:2j per pair (8 DPP vs 16 DPP + 8 cvt).
// Precision: x-path and biases stay fp32; dot products accumulate fp32; fp16
// quantization (rel 2.4e-4) on w/h -> expected absmax ~3-9e-4 < 1.35e-3 thr.
__global__ __launch_bounds__(256)
__attribute__((amdgpu_waves_per_eu(1, 1)))
void lstm_seq_kernel(const float* __restrict__ input,
                     const float* __restrict__ W_ih1, const float* __restrict__ W_hh1,
                     const float* __restrict__ b_ih1, const float* __restrict__ b_hh1,
                     const float* __restrict__ W_ih2, const float* __restrict__ W_hh2,
                     const float* __restrict__ b_ih2, const float* __restrict__ b_hh2,
                     const float* __restrict__ W_lin, const float* __restrict__ b_lin,
                     float* __restrict__ out)
{
    const int tid  = threadIdx.x;
    const int wq   = tid >> 6;
    const int lane = tid & 63;
    const int g    = lane >> 4;       // batch subgroup == DPP row
    const int k    = lane & 15;       // hidden unit / time-slot (15 = pad unit)
    const int b0   = (blockIdx.x * 4 + wq) * 4;

    const bool pad = (k >= HID);
    const float m  = pad ? 0.0f : 1.0f;
    const int  kk  = pad ? 0 : k;

    // act-input scale per gate (i,f,g,o): sigm rows -log2e, tanh row -2log2e
    const float L2E = 1.442695040888963f;
    const float sA[4] = {-L2E, -L2E, -2.0f * L2E, -L2E};

    // packed fp16 weight pairs: [gate][pair j] = {w[2j], w[2j+1]}, elem 15 = 0
    v2h w1[4][8], w2i[4][8], w2h[4][8];
    float wih1[4], bb1[4], bb2[4];
    #pragma unroll
    for (int gi = 0; gi < 4; ++gi) {
        const int row = gi * HID + kk;
        const float s = m * sA[gi];
        wih1[gi] = s * W_ih1[row];
        bb1[gi]  = s * (b_ih1[row] + b_hh1[row]);
        bb2[gi]  = s * (b_ih2[row] + b_hh2[row]);
        #pragma unroll
        for (int j = 0; j < 8; ++j) {
            const int c0 = 2 * j, c1i = 2 * j + 1;
            w1 [gi][j] = (v2h){(_Float16)(s * W_hh1[row * HID + c0]),
                               (_Float16)((c1i < HID) ? s * W_hh1[row * HID + c1i] : 0.0f)};
            w2i[gi][j] = (v2h){(_Float16)(s * W_ih2[row * HID + c0]),
                               (_Float16)((c1i < HID) ? s * W_ih2[row * HID + c1i] : 0.0f)};
            w2h[gi][j] = (v2h){(_Float16)(s * W_hh2[row * HID + c0]),
                               (_Float16)((c1i < HID) ? s * W_hh2[row * HID + c1i] : 0.0f)};
        }
    }
    const float wl   = m * W_lin[kk];
    const float blin = b_lin[0];

    // build packed-pair register from scalar h: lane k -> {h16[k], h16[k+1]}
    // (even lanes 2j hold pair j; lane15 gets {h15, 0} via bound_ctrl)
    auto packh = [&](float h) -> int {
        const _Float16 hh = (_Float16)h;                   // v_cvt_f16_f32 (RNE)
        const int lo  = (int)(unsigned short)__builtin_bit_cast(unsigned short, hh);
        const int hi  = dppi<0x101>(lo);                   // row_shl:1 -> lane k+1's h16
        const v2h pr  = {__builtin_bit_cast(_Float16, (unsigned short)lo),
                         __builtin_bit_cast(_Float16, (unsigned short)hi)};
        return __builtin_bit_cast(int, pr);                // v_pack_b32_f16
    };

    int hpk1 = packh(0.0f), hpk2 = packh(0.0f);  // packed h1/h2 (persist across steps)
    float c1 = 0.0f, c2 = 0.0f, outv = 0.0f;

    auto step = [&](float x, int sub, float& oreg) {
        // ---- broadcast h1 pairs (one DPP each) and do layer-1 pre-acts ----
        float a0 = __builtin_fmaf(wih1[0], x, bb1[0]);
        float a1 = __builtin_fmaf(wih1[1], x, bb1[1]);
        float a2 = __builtin_fmaf(wih1[2], x, bb1[2]);
        float a3 = __builtin_fmaf(wih1[3], x, bb1[3]);
        unroll_for<0, 8>([&](auto jc) {
            constexpr int j = decltype(jc)::v;
            const v2h hb = __builtin_bit_cast(v2h, dppi<0x150 + 2*j>(hpk1));
            a0 = fdot2(w1[0][j], hb, a0);
            a1 = fdot2(w1[1][j], hb, a1);
            a2 = fdot2(w1[2][j], hb, a2);
            a3 = fdot2(w1[3][j], hb, a3);
        });

        // ---- layer-2 hh part (prev h2; overlaps L1 act latency below) ----
        float d0 = bb2[0], d1 = bb2[1], d2 = bb2[2], d3 = bb2[3];
        unroll_for<0, 8>([&](auto jc) {
            constexpr int j = decltype(jc)::v;
            const v2h hb = __builtin_bit_cast(v2h, dppi<0x150 + 2*j>(hpk2));
            d0 = fdot2(w2h[0][j], hb, d0);
            d1 = fdot2(w2h[1][j], hb, d1);
            d2 = fdot2(w2h[2][j], hb, d2);
            d3 = fdot2(w2h[3][j], hb, d3);
        });

        // ---- layer-1 activations, c1, h1 ----
        const float ig = rcp_(1.0f + exp2_(a0));
        const float fg = rcp_(1.0f + exp2_(a1));
        const float gg = __builtin_fmaf(2.0f, rcp_(1.0f + exp2_(a2)), -1.0f);
        const float og = rcp_(1.0f + exp2_(a3));
        c1 = __builtin_fmaf(fg, c1, ig * gg);
        const float h1n = og * tanh_(c1);

        // ---- pack h1 once (used by L2-ih now and L1-hh next step) ----
        hpk1 = packh(h1n);
        unroll_for<0, 8>([&](auto jc) {
            constexpr int j = decltype(jc)::v;
            const v2h hb = __builtin_bit_cast(v2h, dppi<0x150 + 2*j>(hpk1));
            d0 = fdot2(w2i[0][j], hb, d0);
            d1 = fdot2(w2i[1][j], hb, d1);
            d2 = fdot2(w2i[2][j], hb, d2);
            d3 = fdot2(w2i[3][j], hb, d3);
        });

        // ---- layer-2 activations, c2, h2 ----
        const float i2 = rcp_(1.0f + exp2_(d0));
        const float f2 = rcp_(1.0f + exp2_(d1));
        const float g2 = __builtin_fmaf(2.0f, rcp_(1.0f + exp2_(d2)), -1.0f);
        const float o2 = rcp_(1.0f + exp2_(d3));
        c2 = __builtin_fmaf(f2, c2, i2 * g2);
        const float h2n = o2 * tanh_(c2);
        hpk2 = packh(h2n);

        // ---- out = <W_lin, h2> + b (fp32 DPP row reduction); keep own slot ----
        const float ov = row_sum_bcast(wl * h2n) + blin;
        oreg = (k == sub) ? ov : oreg;

        outv = ov;
    };

    const size_t inb  = (size_t)(b0 + g) * TMAIN + k;
    const size_t outb = (size_t)(b0 + g) * OUTW  + k;

    // ---- main: 64 chunks of 16 steps; x prefetched one chunk ahead ----
    float xnext = input[inb];
    #pragma unroll 1
    for (int ch = 0; ch < TMAIN / 16; ++ch) {
        const float xcur = xnext;
        const int tn = (ch < TMAIN / 16 - 1) ? (ch + 1) * 16 : ch * 16; // clamped
        xnext = input[inb + tn];
        float oreg = 0.0f;
        unroll_for<0, 16>([&](auto sc) {
            constexpr int s = decltype(sc)::v;
            step(dppf<0x150 + s>(xcur), s, oreg);   // x[tc+s] bcast to the row
        });
        out[outb + ch * 16] = oreg;                 // coalesced, 16 t per lane
    }

    // ---- future: x = previous out (row-uniform in outv already) ----
    #pragma unroll 1
    for (int ch = 0; ch < FUT / 16; ++ch) {
        float oreg = 0.0f;
        unroll_for<0, 16>([&](auto sc) {
            constexpr int s = decltype(sc)::v;
            step(outv, s, oreg);
        });
        out[outb + TMAIN + ch * 16] = oreg;
    }
}

extern "C" void kernel_launch(void* const* d_in, const int* in_sizes, int n_in,
                              void* d_out, int out_size, void* d_ws, size_t ws_size,
                              hipStream_t stream)
{
    const float* input = (const float*)d_in[0];
    const float* W_ih1 = (const float*)d_in[1];
    const float* W_hh1 = (const float*)d_in[2];
    const float* b_ih1 = (const float*)d_in[3];
    const float* b_hh1 = (const float*)d_in[4];
    const float* W_ih2 = (const float*)d_in[5];
    const float* W_hh2 = (const float*)d_in[6];
    const float* b_ih2 = (const float*)d_in[7];
    const float* b_hh2 = (const float*)d_in[8];
    const float* W_lin = (const float*)d_in[9];
    const float* b_lin = (const float*)d_in[10];
    // d_in[11] = future (=64), compiled in as FUT

    // 4096 batches / (4 per wave * 4 waves per block) = 256 blocks
    lstm_seq_kernel<<<256, 256, 0, stream>>>(
        input, W_ih1, W_hh1, b_ih1, b_hh1,
        W_ih2, W_hh2, b_ih2, b_hh2, W_lin, b_lin,
        (float*)d_out);
}

// Round 10
// 471.389 us; speedup vs baseline: 1.7642x; 1.0125x over previous
//
#include <hip/hip_runtime.h>

#define HID   15
#define TMAIN 1024
#define FUT   64
#define OUTW  (TMAIN + FUT)   // 1088

typedef _Float16 v2h __attribute__((ext_vector_type(2)));

__device__ __forceinline__ float rcp_(float x)  { return __builtin_amdgcn_rcpf(x); }
__device__ __forceinline__ float exp2_(float x) { return __builtin_amdgcn_exp2f(x); }
__device__ __forceinline__ float tanh_(float x) {
    return __builtin_fmaf(2.0f, rcp_(1.0f + exp2_(x * -2.885390081777927f)), -1.0f);
}

template<int I> struct ic { static constexpr int v = I; };
template<int J, int N, class F>
__device__ __forceinline__ void unroll_for(F&& f) {
    if constexpr (J < N) { f(ic<J>{}); unroll_for<J + 1, N>(f); }
}

// DPP ctrl: 0x150+j = row_newbcast:j (CDNA), 0x110+n = row_shr:n, 0x101 = shl1
template<int CTRL>
__device__ __forceinline__ int dppi(int x) {
    return __builtin_amdgcn_update_dpp(0, x, CTRL, 0xF, 0xF, true);
}
template<int CTRL>
__device__ __forceinline__ float dppf(float x) {
    return __int_as_float(dppi<CTRL>(__float_as_int(x)));
}
__device__ __forceinline__ float row_sum_bcast(float p) {
    p += dppf<0x111>(p);
    p += dppf<0x112>(p);
    p += dppf<0x114>(p);
    p += dppf<0x118>(p);
    return dppf<0x15F>(p);
}
__device__ __forceinline__ float fdot2(v2h a, v2h b, float c) {
    return __builtin_amdgcn_fdot2(a, b, c, false);
}
// cvt_pkrtz returns __fp16x2; bit-cast to our v2h (same bits)
__device__ __forceinline__ v2h pkrtz(float lo, float hi) {
    return __builtin_bit_cast(v2h, __builtin_amdgcn_cvt_pkrtz(lo, hi));
}

// R9 = R8 (n=4, all-register, fdot2) minus redundant per-step work:
//  - hb1[8] broadcast pairs built ONCE after h1n; used by L2-ih(t) AND
//    L1-hh(t+1) (both consume h1(t)) -> -8 DPP/step.
//  - x folded into the K-dim: w1[g][7] = {W_hh1[..14], W_ih1[row]} and
//    hb1[7].y <- x(t+1) at step end (pkrtz(bcast14(h1n), xv)); w2i/w2h
//    keep .y=0 so the shared pair is inert for them. Kills the 4 x-FMAs.
//    Future phase: xv = ov (ready at the fix point -> clean out->x feedback).
// Revised HW model (R7/R8 busy reconciliation): v_dot2_f32_f16 is HALF-RATE
// (4cyc) -- VALU MAC ceiling is 32 MACs/cyc/SIMD in every dtype; dot2's win
// was the removed adds + regs. Floor ~660 busy cyc/step for this mapping.
__global__ __launch_bounds__(256)
__attribute__((amdgpu_waves_per_eu(1, 1)))
void lstm_seq_kernel(const float* __restrict__ input,
                     const float* __restrict__ W_ih1, const float* __restrict__ W_hh1,
                     const float* __restrict__ b_ih1, const float* __restrict__ b_hh1,
                     const float* __restrict__ W_ih2, const float* __restrict__ W_hh2,
                     const float* __restrict__ b_ih2, const float* __restrict__ b_hh2,
                     const float* __restrict__ W_lin, const float* __restrict__ b_lin,
                     float* __restrict__ out)
{
    const int tid  = threadIdx.x;
    const int wq   = tid >> 6;
    const int lane = tid & 63;
    const int g    = lane >> 4;       // batch subgroup == DPP row
    const int k    = lane & 15;       // hidden unit / time-slot (15 = pad unit)
    const int b0   = (blockIdx.x * 4 + wq) * 4;

    const bool pad = (k >= HID);
    const float m  = pad ? 0.0f : 1.0f;
    const int  kk  = pad ? 0 : k;

    const float L2E = 1.442695040888963f;
    const float sA[4] = {-L2E, -L2E, -2.0f * L2E, -L2E};

    // packed fp16 weight pairs; pair 7 of w1 carries the x weight in .y
    v2h w1[4][8], w2i[4][8], w2h[4][8];
    float bb1[4], bb2[4];
    #pragma unroll
    for (int gi = 0; gi < 4; ++gi) {
        const int row = gi * HID + kk;
        const float s = m * sA[gi];
        bb1[gi] = s * (b_ih1[row] + b_hh1[row]);
        bb2[gi] = s * (b_ih2[row] + b_hh2[row]);
        #pragma unroll
        for (int j = 0; j < 8; ++j) {
            const int c0 = 2 * j, c1i = 2 * j + 1;
            w1 [gi][j] = (v2h){(_Float16)(s * W_hh1[row * HID + c0]),
                               (_Float16)((c1i < HID) ? s * W_hh1[row * HID + c1i]
                                                      : s * W_ih1[row])};   // x slot
            w2i[gi][j] = (v2h){(_Float16)(s * W_ih2[row * HID + c0]),
                               (_Float16)((c1i < HID) ? s * W_ih2[row * HID + c1i] : 0.0f)};
            w2h[gi][j] = (v2h){(_Float16)(s * W_hh2[row * HID + c0]),
                               (_Float16)((c1i < HID) ? s * W_hh2[row * HID + c1i] : 0.0f)};
        }
    }
    const float wl   = m * W_lin[kk];
    const float blin = b_lin[0];

    // lane k -> packed pair {h16[k], h16[k+1]} (lane15 edge -> 0 via bound_ctrl)
    auto packh = [&](float h) -> int {
        const _Float16 hh = (_Float16)h;                   // RNE
        const int lo = (int)(unsigned short)__builtin_bit_cast(unsigned short, hh);
        const int hi = dppi<0x101>(lo);
        const v2h pr = {__builtin_bit_cast(_Float16, (unsigned short)lo),
                        __builtin_bit_cast(_Float16, (unsigned short)(hi & 0xFFFF))};
        return __builtin_bit_cast(int, pr);
    };

    v2h hb1[8];                        // h1 broadcast pairs (persist across steps)
    #pragma unroll
    for (int j = 0; j < 8; ++j) hb1[j] = (v2h){(_Float16)0.0f, (_Float16)0.0f};
    int hpk2 = 0;                      // packed h2 = {0,0}
    float c1 = 0.0f, c2 = 0.0f, outv = 0.0f;

    // one step. S = slot in 16-chunk (compile-time); USE_OV: xv for the next
    // step's pair-7 fix comes from ov (future / last main step) else xvpre.
    auto step = [&](auto Sc, auto UseOvC, float xvpre, float& oreg) {
        constexpr int  S      = decltype(Sc)::v;
        constexpr bool USE_OV = decltype(UseOvC)::v;

        // ---- layer-1 pre-acts from persisted hb1 (pair7.y carries x(t)) ----
        float a0 = bb1[0], a1 = bb1[1], a2 = bb1[2], a3 = bb1[3];
        unroll_for<0, 8>([&](auto jc) {
            constexpr int j = decltype(jc)::v;
            a0 = fdot2(w1[0][j], hb1[j], a0);
            a1 = fdot2(w1[1][j], hb1[j], a1);
            a2 = fdot2(w1[2][j], hb1[j], a2);
            a3 = fdot2(w1[3][j], hb1[j], a3);
        });

        // ---- layer-2 hh part (prev h2; fills L1-act latency) ----
        float d0 = bb2[0], d1 = bb2[1], d2 = bb2[2], d3 = bb2[3];
        unroll_for<0, 8>([&](auto jc) {
            constexpr int j = decltype(jc)::v;
            const v2h hb = __builtin_bit_cast(v2h, dppi<0x150 + 2*j>(hpk2));
            d0 = fdot2(w2h[0][j], hb, d0);
            d1 = fdot2(w2h[1][j], hb, d1);
            d2 = fdot2(w2h[2][j], hb, d2);
            d3 = fdot2(w2h[3][j], hb, d3);
        });

        // ---- layer-1 activations, c1, h1 ----
        const float ig = rcp_(1.0f + exp2_(a0));
        const float fg = rcp_(1.0f + exp2_(a1));
        const float gg = __builtin_fmaf(2.0f, rcp_(1.0f + exp2_(a2)), -1.0f);
        const float og = rcp_(1.0f + exp2_(a3));
        c1 = __builtin_fmaf(fg, c1, ig * gg);
        const float h1n = og * tanh_(c1);

        // ---- build hb1 once (L2-ih now; L1-hh next step) ----
        const int hpk1 = packh(h1n);
        unroll_for<0, 8>([&](auto jc) {
            constexpr int j = decltype(jc)::v;
            hb1[j] = __builtin_bit_cast(v2h, dppi<0x150 + 2*j>(hpk1));
        });
        unroll_for<0, 8>([&](auto jc) {
            constexpr int j = decltype(jc)::v;
            d0 = fdot2(w2i[0][j], hb1[j], d0);
            d1 = fdot2(w2i[1][j], hb1[j], d1);
            d2 = fdot2(w2i[2][j], hb1[j], d2);
            d3 = fdot2(w2i[3][j], hb1[j], d3);
        });

        // ---- layer-2 activations, c2, h2 ----
        const float i2 = rcp_(1.0f + exp2_(d0));
        const float f2 = rcp_(1.0f + exp2_(d1));
        const float g2 = __builtin_fmaf(2.0f, rcp_(1.0f + exp2_(d2)), -1.0f);
        const float o2 = rcp_(1.0f + exp2_(d3));
        c2 = __builtin_fmaf(f2, c2, i2 * g2);
        const float h2n = o2 * tanh_(c2);
        hpk2 = packh(h2n);

        // ---- out = <W_lin, h2> + b; keep own slot ----
        const float ov = row_sum_bcast(wl * h2n) + blin;
        oreg = (k == S) ? ov : oreg;

        // ---- pair-7 fix: {h1[14], x(t+1)} for the next step's L1 ----
        const float xv = USE_OV ? ov : xvpre;
        hb1[7] = pkrtz(dppf<0x15E>(h1n), xv);

        outv = ov;
    };

    const size_t inb  = (size_t)(b0 + g) * TMAIN + k;
    const size_t outb = (size_t)(b0 + g) * OUTW  + k;

    float xcur = input[inb];
    // prologue: x(0) into pair7.y
    hb1[7] = pkrtz(0.0f, dppf<0x150>(xcur));

    // ---- main: 64 chunks of 16 steps; x prefetched one chunk ahead ----
    #pragma unroll 1
    for (int ch = 0; ch < TMAIN / 16; ++ch) {
        const bool last = (ch == TMAIN / 16 - 1);
        const float xnext = input[inb + (last ? ch : ch + 1) * 16];
        float oreg = 0.0f;
        unroll_for<0, 16>([&](auto sc) {
            constexpr int s = decltype(sc)::v;
            if constexpr (s < 15) {
                step(sc, ic<0>{}, dppf<0x150 + s + 1>(xcur), oreg);
            } else {
                // s==15: next x comes from the next chunk (or ov on last chunk)
                if (last) step(sc, ic<1>{}, 0.0f, oreg);
                else      step(sc, ic<0>{}, dppf<0x150>(xnext), oreg);
            }
        });
        out[outb + ch * 16] = oreg;
        xcur = xnext;
    }

    // ---- future: x = previous out (handled by USE_OV pair-7 fix) ----
    #pragma unroll 1
    for (int ch = 0; ch < FUT / 16; ++ch) {
        float oreg = 0.0f;
        unroll_for<0, 16>([&](auto sc) {
            step(sc, ic<1>{}, 0.0f, oreg);
        });
        out[outb + TMAIN + ch * 16] = oreg;
    }
}

extern "C" void kernel_launch(void* const* d_in, const int* in_sizes, int n_in,
                              void* d_out, int out_size, void* d_ws, size_t ws_size,
                              hipStream_t stream)
{
    const float* input = (const float*)d_in[0];
    const float* W_ih1 = (const float*)d_in[1];
    const float* W_hh1 = (const float*)d_in[2];
    const float* b_ih1 = (const float*)d_in[3];
    const float* b_hh1 = (const float*)d_in[4];
    const float* W_ih2 = (const float*)d_in[5];
    const float* W_hh2 = (const float*)d_in[6];
    const float* b_ih2 = (const float*)d_in[7];
    const float* b_hh2 = (const float*)d_in[8];
    const float* W_lin = (const float*)d_in[9];
    const float* b_lin = (const float*)d_in[10];
    // d_in[11] = future (=64), compiled in as FUT

    // 4096 batches / (4 per wave * 4 waves per block) = 256 blocks
    lstm_seq_kernel<<<256, 256, 0, stream>>>(
        input, W_ih1, W_hh1, b_ih1, b_hh1,
        W_ih2, W_hh2, b_ih2, b_hh2, W_lin, b_lin,
        (float*)d_out);
}